// Round 1
// baseline (660.796 us; speedup 1.0000x reference)
//
#include <hip/hip_runtime.h>

#define HW 9216
#define WIDTH 96
#define NCLS 20
#define NOUT 25   // 1 obj + 20 cls + 4 reg
#define CAP 1024

// ---------------------------------------------------------------------------
// K1: fused GEMM (9216 x 512 x 25) + decode.
// Block = 256 threads = 8 channel-chunks x 32 positions. Deterministic
// reduction order: sequential within chunk, then chunks 0..7 ascending.
// ---------------------------------------------------------------------------
__global__ __launch_bounds__(256) void decode_kernel(
    const float* __restrict__ cls_feat, const float* __restrict__ reg_feat,
    const float* __restrict__ obj_w, const float* __restrict__ obj_b,
    const float* __restrict__ cls_w, const float* __restrict__ cls_b,
    const float* __restrict__ reg_w, const float* __restrict__ reg_b,
    float* __restrict__ out, unsigned* __restrict__ cnt,
    unsigned long long* __restrict__ keys)
{
    __shared__ float lds[512 * 28];   // weights transposed [c][28]; reused for partials
    const int tid = threadIdx.x;

    // stage weights: lds[c*28 + o], o: 0=obj, 1..20=cls, 21..24=reg
    for (int i = tid; i < 512 * 25; i += 256) {
        int c = i / 25, o = i - c * 25;
        float v;
        if (o == 0)        v = obj_w[c];
        else if (o < 21)   v = cls_w[(o - 1) * 512 + c];
        else               v = reg_w[(o - 21) * 512 + c];
        lds[c * 28 + o] = v;
    }
    __syncthreads();

    const int posL  = tid & 31;
    const int chunk = tid >> 5;
    const int p     = blockIdx.x * 32 + posL;
    const int cb    = chunk * 64;

    float acc[NOUT];
#pragma unroll
    for (int o = 0; o < NOUT; ++o) acc[o] = 0.f;

    const float* cf = cls_feat + cb * HW + p;
    const float* rf = reg_feat + cb * HW + p;

#pragma unroll 4
    for (int k = 0; k < 64; ++k) {
        float f = cf[k * HW];
        float g = rf[k * HW];
        const float4* w = (const float4*)(lds + (cb + k) * 28);
        float4 w0 = w[0], w1 = w[1], w2 = w[2], w3 = w[3], w4v = w[4], w5 = w[5], w6 = w[6];
        acc[0]  += f * w0.x;  acc[1]  += f * w0.y;  acc[2]  += f * w0.z;  acc[3]  += f * w0.w;
        acc[4]  += f * w1.x;  acc[5]  += f * w1.y;  acc[6]  += f * w1.z;  acc[7]  += f * w1.w;
        acc[8]  += f * w2.x;  acc[9]  += f * w2.y;  acc[10] += f * w2.z;  acc[11] += f * w2.w;
        acc[12] += f * w3.x;  acc[13] += f * w3.y;  acc[14] += f * w3.z;  acc[15] += f * w3.w;
        acc[16] += f * w4v.x; acc[17] += f * w4v.y; acc[18] += f * w4v.z; acc[19] += f * w4v.w;
        acc[20] += f * w5.x;
        acc[21] += g * w5.y;  acc[22] += g * w5.z;  acc[23] += g * w5.w;  acc[24] += g * w6.x;
    }

    __syncthreads();                    // weights no longer needed; reuse LDS
    float* part = lds;                  // [chunk][pos][25]
#pragma unroll
    for (int o = 0; o < NOUT; ++o) part[(chunk * 32 + posL) * NOUT + o] = acc[o];
    __syncthreads();

    float* dots = lds + 8 * 32 * NOUT;  // [pos][25]
    for (int t = tid; t < 32 * NOUT; t += 256) {
        int pos = t / NOUT, o = t - pos * NOUT;
        float s = 0.f;
#pragma unroll
        for (int c2 = 0; c2 < 8; ++c2) s += part[(c2 * 32 + pos) * NOUT + o];
        dots[t] = s;                    // t == pos*NOUT + o
    }
    __syncthreads();

    if (tid < 32) {
        const int pos = tid;
        const int pp  = blockIdx.x * 32 + pos;
        const float* d = dots + pos * NOUT;

        float obj  = d[0] + obj_b[0];
        float best = d[1] + cls_b[0];
        int   bk   = 0;
#pragma unroll
        for (int k = 1; k < NCLS; ++k) {
            float v = d[1 + k] + cls_b[k];
            if (v > best) { best = v; bk = k; }   // strict > == first-max (jnp.argmax)
        }
        float sobj  = 1.f / (1.f + expf(-obj));
        float scls  = 1.f / (1.f + expf(-best));  // sigmoid monotone -> max commutes
        float score = sobj * scls;

        float r0 = d[21] + reg_b[0], r1 = d[22] + reg_b[1];
        float r2 = d[23] + reg_b[2], r3 = d[24] + reg_b[3];
        float gx = (float)(pp % WIDTH), gy = (float)(pp / WIDTH);
        float cx = (1.f / (1.f + expf(-r0)) + gx) * 32.f;
        float cy = (1.f / (1.f + expf(-r1)) + gy) * 32.f;
        float bw = expf(r2) * 32.f;
        float bh = expf(r3) * 32.f;
        float hx = 0.5f * bw, hy = 0.5f * bh;

        ((float4*)out)[pp] = make_float4(cx - hx, cy - hy, cx + hx, cy + hy);
        out[HW * 4 + pp] = score;
        out[HW * 5 + pp] = (float)bk;
        out[HW * 6 + pp] = 0.f;         // keep default; NMS sets 1s

        if (score >= 0.01f) {
            unsigned slot = atomicAdd(&cnt[bk], 1u);
            if (slot < CAP) {
                // ascending u64 key == (score desc, idx asc) — matches stable argsort
                unsigned sb = __float_as_uint(score) ^ 0xffffffffu;
                keys[bk * CAP + slot] = ((unsigned long long)sb << 32) | (unsigned)pp;
            }
        }
    }
}

// ---------------------------------------------------------------------------
// K2: per-class bitonic sort of keys (pad to 1024 with UINT64_MAX).
// Unique keys -> deterministic result despite atomic insertion order.
// ---------------------------------------------------------------------------
__global__ __launch_bounds__(256) void sort_kernel(
    const unsigned* __restrict__ cnt, unsigned long long* __restrict__ keys)
{
    __shared__ unsigned long long a[CAP];
    const int c = blockIdx.x, tid = threadIdx.x;
    unsigned m = cnt[c]; if (m > CAP) m = CAP;

    for (int t = tid; t < CAP; t += 256)
        a[t] = (t < (int)m) ? keys[c * CAP + t] : 0xFFFFFFFFFFFFFFFFull;
    __syncthreads();

    for (int k = 2; k <= CAP; k <<= 1) {
        for (int j = k >> 1; j > 0; j >>= 1) {
            for (int t = tid; t < CAP; t += 256) {
                int ixj = t ^ j;
                if (ixj > t) {
                    unsigned long long x = a[t], y = a[ixj];
                    bool up = ((t & k) == 0);
                    if ((x > y) == up) { a[t] = y; a[ixj] = x; }
                }
            }
            __syncthreads();
        }
    }
    for (int t = tid; t < (int)m; t += 256) keys[c * CAP + t] = a[t];
}

// ---------------------------------------------------------------------------
// K3: per-class greedy NMS, one 64-lane wave per class, lockstep (no barriers
// in the scan). Lane l owns boxes j = s*64+l (s<16) in registers; suppression
// flags live in a per-lane 16-bit mask, broadcast via __shfl.
// ---------------------------------------------------------------------------
__global__ __launch_bounds__(64) void nms_kernel(
    const unsigned* __restrict__ cnt, const unsigned long long* __restrict__ keys,
    const float* __restrict__ bboxes, float* __restrict__ keep)
{
    __shared__ float4   lbox[CAP];
    __shared__ unsigned lidx[CAP];
    const int c = blockIdx.x, lane = threadIdx.x;
    int m = (int)cnt[c]; if (m > CAP) m = CAP;

    float bx1[16], by1[16], bx2[16], by2[16];
#pragma unroll
    for (int s = 0; s < 16; ++s) {
        int j = s * 64 + lane;
        if (j < m) {
            unsigned idx = (unsigned)(keys[c * CAP + j] & 0xffffffffu);
            float4 b = ((const float4*)bboxes)[idx];
            lbox[j] = b; lidx[j] = idx;
            bx1[s] = b.x; by1[s] = b.y; bx2[s] = b.z; by2[s] = b.w;
        }
    }
    __syncthreads();

    unsigned sup = 0;   // bit s: box s*64+lane suppressed
    for (int i = 0; i < m; ++i) {
        const int owner = i & 63, slot = i >> 6;
        unsigned smi = (unsigned)__shfl((int)sup, owner);   // uniform
        if (!((smi >> slot) & 1u)) {                        // box i is kept
            float4 bi = lbox[i];                            // uniform LDS broadcast
            if (lane == owner) keep[lidx[i]] = 1.0f;
            float ai = (bi.z - bi.x) * (bi.w - bi.y);
#pragma unroll
            for (int s = 0; s < 16; ++s) {
                int j = s * 64 + lane;
                if (j > i && j < m && !((sup >> s) & 1u)) {
                    float iw = fminf(bx2[s], bi.z) - fmaxf(bx1[s], bi.x);
                    float ih = fminf(by2[s], bi.w) - fmaxf(by1[s], bi.y);
                    iw = fmaxf(iw, 1e-10f);
                    ih = fmaxf(ih, 1e-10f);
                    float inter = iw * ih;
                    float aj = (bx2[s] - bx1[s]) * (by2[s] - by1[s]);
                    float iou = inter / (ai + aj - inter);
                    if (iou > 0.5f) sup |= (1u << s);
                }
            }
        }
    }
}

// ---------------------------------------------------------------------------
extern "C" void kernel_launch(void* const* d_in, const int* in_sizes, int n_in,
                              void* d_out, int out_size, void* d_ws, size_t ws_size,
                              hipStream_t stream)
{
    const float* cls_feat = (const float*)d_in[0];
    const float* reg_feat = (const float*)d_in[1];
    const float* obj_w    = (const float*)d_in[2];
    const float* obj_b    = (const float*)d_in[3];
    const float* cls_w    = (const float*)d_in[4];
    const float* cls_b    = (const float*)d_in[5];
    const float* reg_w    = (const float*)d_in[6];
    const float* reg_b    = (const float*)d_in[7];

    float* out = (float*)d_out;
    unsigned* cnt = (unsigned*)d_ws;
    unsigned long long* keys = (unsigned long long*)((char*)d_ws + 256);

    hipMemsetAsync(d_ws, 0, 256, stream);   // zero per-class counters

    decode_kernel<<<288, 256, 0, stream>>>(cls_feat, reg_feat, obj_w, obj_b,
                                           cls_w, cls_b, reg_w, reg_b,
                                           out, cnt, keys);
    sort_kernel<<<NCLS, 256, 0, stream>>>(cnt, keys);
    nms_kernel<<<NCLS, 64, 0, stream>>>(cnt, keys, out, out + HW * 6);
}

// Round 2
// 296.884 us; speedup vs baseline: 2.2258x; 2.2258x over previous
//
#include <hip/hip_runtime.h>

#define HW 9216
#define WIDTH 96
#define NCLS 20
#define NOUT 25   // 1 obj + 20 cls + 4 reg
#define CAP 1024
#define TILE 128  // mask rows per tile (2 sweep words)
#define NWMAX 16  // CAP/64 words per mask row

// ---------------------------------------------------------------------------
// K1: fused GEMM (9216 x 512 x 25) + decode. Identical arithmetic/reduction
// order to the round-1 passing kernel (bit-exact); only the weight-staging
// global read pattern changed to be coalesced (o-major -> consecutive c).
// ---------------------------------------------------------------------------
__global__ __launch_bounds__(256) void decode_kernel(
    const float* __restrict__ cls_feat, const float* __restrict__ reg_feat,
    const float* __restrict__ obj_w, const float* __restrict__ obj_b,
    const float* __restrict__ cls_w, const float* __restrict__ cls_b,
    const float* __restrict__ reg_w, const float* __restrict__ reg_b,
    float* __restrict__ out, unsigned* __restrict__ cnt,
    unsigned long long* __restrict__ keys)
{
    __shared__ float lds[512 * 28];   // weights [c][28]; reused for partials
    const int tid = threadIdx.x;

    // stage weights coalesced: i = o*512 + c, consecutive lanes read consecutive c
    for (int i = tid; i < 25 * 512; i += 256) {
        int o = i >> 9, c = i & 511;
        float v;
        if (o == 0)        v = obj_w[c];
        else if (o < 21)   v = cls_w[(o - 1) * 512 + c];
        else               v = reg_w[(o - 21) * 512 + c];
        lds[c * 28 + o] = v;
    }
    __syncthreads();

    const int posL  = tid & 31;
    const int chunk = tid >> 5;
    const int p     = blockIdx.x * 32 + posL;
    const int cb    = chunk * 64;

    float acc[NOUT];
#pragma unroll
    for (int o = 0; o < NOUT; ++o) acc[o] = 0.f;

    const float* cf = cls_feat + cb * HW + p;
    const float* rf = reg_feat + cb * HW + p;

#pragma unroll 4
    for (int k = 0; k < 64; ++k) {
        float f = cf[k * HW];
        float g = rf[k * HW];
        const float4* w = (const float4*)(lds + (cb + k) * 28);
        float4 w0 = w[0], w1 = w[1], w2 = w[2], w3 = w[3], w4v = w[4], w5 = w[5], w6 = w[6];
        acc[0]  += f * w0.x;  acc[1]  += f * w0.y;  acc[2]  += f * w0.z;  acc[3]  += f * w0.w;
        acc[4]  += f * w1.x;  acc[5]  += f * w1.y;  acc[6]  += f * w1.z;  acc[7]  += f * w1.w;
        acc[8]  += f * w2.x;  acc[9]  += f * w2.y;  acc[10] += f * w2.z;  acc[11] += f * w2.w;
        acc[12] += f * w3.x;  acc[13] += f * w3.y;  acc[14] += f * w3.z;  acc[15] += f * w3.w;
        acc[16] += f * w4v.x; acc[17] += f * w4v.y; acc[18] += f * w4v.z; acc[19] += f * w4v.w;
        acc[20] += f * w5.x;
        acc[21] += g * w5.y;  acc[22] += g * w5.z;  acc[23] += g * w5.w;  acc[24] += g * w6.x;
    }

    __syncthreads();                    // weights done; reuse LDS
    float* part = lds;                  // [chunk][pos][25]
#pragma unroll
    for (int o = 0; o < NOUT; ++o) part[(chunk * 32 + posL) * NOUT + o] = acc[o];
    __syncthreads();

    float* dots = lds + 8 * 32 * NOUT;  // [pos][25]
    for (int t = tid; t < 32 * NOUT; t += 256) {
        int pos = t / NOUT, o = t - pos * NOUT;
        float s = 0.f;
#pragma unroll
        for (int c2 = 0; c2 < 8; ++c2) s += part[(c2 * 32 + pos) * NOUT + o];
        dots[t] = s;
    }
    __syncthreads();

    if (tid < 32) {
        const int pos = tid;
        const int pp  = blockIdx.x * 32 + pos;
        const float* d = dots + pos * NOUT;

        float obj  = d[0] + obj_b[0];
        float best = d[1] + cls_b[0];
        int   bk   = 0;
#pragma unroll
        for (int k = 1; k < NCLS; ++k) {
            float v = d[1 + k] + cls_b[k];
            if (v > best) { best = v; bk = k; }   // strict > == first-max
        }
        float sobj  = 1.f / (1.f + expf(-obj));
        float scls  = 1.f / (1.f + expf(-best));
        float score = sobj * scls;

        float r0 = d[21] + reg_b[0], r1 = d[22] + reg_b[1];
        float r2 = d[23] + reg_b[2], r3 = d[24] + reg_b[3];
        float gx = (float)(pp % WIDTH), gy = (float)(pp / WIDTH);
        float cx = (1.f / (1.f + expf(-r0)) + gx) * 32.f;
        float cy = (1.f / (1.f + expf(-r1)) + gy) * 32.f;
        float bw = expf(r2) * 32.f;
        float bh = expf(r3) * 32.f;
        float hx = 0.5f * bw, hy = 0.5f * bh;

        ((float4*)out)[pp] = make_float4(cx - hx, cy - hy, cx + hx, cy + hy);
        out[HW * 4 + pp] = score;
        out[HW * 5 + pp] = (float)bk;
        out[HW * 6 + pp] = 0.f;

        if (score >= 0.01f) {
            unsigned slot = atomicAdd(&cnt[bk], 1u);
            if (slot < CAP) {
                unsigned sb = __float_as_uint(score) ^ 0xffffffffu;
                keys[bk * CAP + slot] = ((unsigned long long)sb << 32) | (unsigned)pp;
            }
        }
    }
}

// ---------------------------------------------------------------------------
// K2: per-class bitonic sort, 512 threads = one compare-exchange per stage.
// ---------------------------------------------------------------------------
__global__ __launch_bounds__(512) void sort_kernel(
    const unsigned* __restrict__ cnt, unsigned long long* __restrict__ keys)
{
    __shared__ unsigned long long a[CAP];
    const int c = blockIdx.x, t = threadIdx.x;
    unsigned m = cnt[c]; if (m > CAP) m = CAP;

    for (int i = t; i < CAP; i += 512)
        a[i] = (i < (int)m) ? keys[c * CAP + i] : 0xFFFFFFFFFFFFFFFFull;
    __syncthreads();

    for (int k = 2; k <= CAP; k <<= 1) {
        for (int j = k >> 1; j > 0; j >>= 1) {
            int i = ((t & ~(j - 1)) << 1) | (t & (j - 1));
            int p = i | j;
            unsigned long long x = a[i], y = a[p];
            bool up = ((i & k) == 0);
            if ((x > y) == up) { a[i] = y; a[p] = x; }
            __syncthreads();
        }
    }
    for (int i = t; i < (int)m; i += 512) keys[c * CAP + i] = a[i];
}

// ---------------------------------------------------------------------------
// K3: mask-matrix NMS. 1024 threads/class.
//  - build: pairwise suppression bits into LDS tile (128 rows x 16 u64),
//    double-buffered; waves 1..15 build tile t+1 while wave 0 sweeps tile t.
//  - sweep: wave 0, `removed` replicated in 16 u64 registers (static index),
//    suppressed box ~3 ops, kept box = 16 uniform LDS words ORed in.
// ---------------------------------------------------------------------------
__device__ __forceinline__ void build_tile(
    int t, int bidx, int nbuild, int lane, int m, int nw,
    const float4* box, unsigned long long (*mb)[NWMAX])
{
    const int base = t * TILE;
    const int rows = min(TILE, m - base);
    if (rows <= 0) return;
    const int totw = rows << 4;                 // NWMAX words per row
    for (int q = bidx; q < totw; q += nbuild) { // q uniform across the wave
        const int il = q >> 4, w = q & (NWMAX - 1);
        unsigned long long word = 0;
        if (w < nw) {
            const float4 bi = box[base + il];   // uniform
            const int j = (w << 6) + lane;
            const float4 bj = box[j];
            const float ai = (bi.z - bi.x) * (bi.w - bi.y);
            const float aj = (bj.z - bj.x) * (bj.w - bj.y);
            float iw = fminf(bi.z, bj.z) - fmaxf(bi.x, bj.x);
            float ih = fminf(bi.w, bj.w) - fmaxf(bi.y, bj.y);
            iw = fmaxf(iw, 1e-10f);
            ih = fmaxf(ih, 1e-10f);
            const float inter = iw * ih;
            const float iou = inter / (ai + aj - inter);
            word = __ballot((j < m) && (iou > 0.5f));
        }
        if (lane == 0) mb[il][w] = word;
    }
}

__global__ __launch_bounds__(1024) void nms_kernel(
    const unsigned* __restrict__ cnt, const unsigned long long* __restrict__ keys,
    const float* __restrict__ bboxes, float* __restrict__ keep)
{
    __shared__ float4 box[CAP];                           // 16 KB
    __shared__ unsigned lidx[CAP];                        // 4 KB
    __shared__ unsigned long long mask[2][TILE][NWMAX];   // 32 KB
    const int c = blockIdx.x, tid = threadIdx.x;
    const int wave = tid >> 6, lane = tid & 63;
    int m = (int)cnt[c]; if (m > CAP) m = CAP;
    const int nw = (m + 63) >> 6;
    const int nt = (m + TILE - 1) / TILE;

    for (int j = tid; j < CAP; j += 1024) {
        if (j < m) {
            unsigned idx = (unsigned)(keys[c * CAP + j] & 0xffffffffu);
            lidx[j] = idx;
            box[j] = ((const float4*)bboxes)[idx];
        } else {
            box[j] = make_float4(0.f, 0.f, 0.f, 0.f);
        }
    }
    __syncthreads();

    // prologue: all 16 waves build tile 0
    build_tile(0, wave, 16, lane, m, nw, box, mask[0]);
    __syncthreads();

    unsigned long long rem[NWMAX];
#pragma unroll
    for (int w = 0; w < NWMAX; ++w) rem[w] = 0;

    for (int t = 0; t < nt; ++t) {
        if (wave == 0) {
            // sweep tile t (words 2t, 2t+1) from buffer t&1
            const unsigned long long (*mb)[NWMAX] = mask[t & 1];
#pragma unroll
            for (int w = 0; w < NWMAX; ++w) {
                if ((w >> 1) != t) continue;        // only this tile's 2 words
                const int i0 = w << 6;
                const int nb = min(64, m - i0);
                unsigned long long cur = rem[w];
                for (int b = 0; b < nb; ++b) {
                    if (!((cur >> b) & 1ull)) {     // box i kept
                        const int i = i0 + b;
                        if (tid == 0) keep[lidx[i]] = 1.0f;
                        const unsigned long long* row = mb[i & (TILE - 1)];
#pragma unroll
                        for (int w2 = 0; w2 < NWMAX; ++w2) rem[w2] |= row[w2];
                        cur = rem[w];
                    }
                }
            }
        } else if (t + 1 < nt) {
            build_tile(t + 1, wave - 1, 15, lane, m, nw, box, mask[(t + 1) & 1]);
        }
        __syncthreads();
    }
}

// ---------------------------------------------------------------------------
extern "C" void kernel_launch(void* const* d_in, const int* in_sizes, int n_in,
                              void* d_out, int out_size, void* d_ws, size_t ws_size,
                              hipStream_t stream)
{
    const float* cls_feat = (const float*)d_in[0];
    const float* reg_feat = (const float*)d_in[1];
    const float* obj_w    = (const float*)d_in[2];
    const float* obj_b    = (const float*)d_in[3];
    const float* cls_w    = (const float*)d_in[4];
    const float* cls_b    = (const float*)d_in[5];
    const float* reg_w    = (const float*)d_in[6];
    const float* reg_b    = (const float*)d_in[7];

    float* out = (float*)d_out;
    unsigned* cnt = (unsigned*)d_ws;
    unsigned long long* keys = (unsigned long long*)((char*)d_ws + 256);

    hipMemsetAsync(d_ws, 0, 256, stream);   // zero per-class counters

    decode_kernel<<<288, 256, 0, stream>>>(cls_feat, reg_feat, obj_w, obj_b,
                                           cls_w, cls_b, reg_w, reg_b,
                                           out, cnt, keys);
    sort_kernel<<<NCLS, 512, 0, stream>>>(cnt, keys);
    nms_kernel<<<NCLS, 1024, 0, stream>>>(cnt, keys, out, out + HW * 6);
}

// Round 3
// 228.312 us; speedup vs baseline: 2.8943x; 1.3003x over previous
//
#include <hip/hip_runtime.h>

#define HW 9216
#define WIDTH 96
#define NCLS 20
#define NOUT 25   // 1 obj + 20 cls + 4 reg
#define CAP 1024
#define NW 16     // CAP/64 mask words per row

// ---------------------------------------------------------------------------
// K1: fused GEMM (9216 x 512 x 25) + decode. BYTE-IDENTICAL to round-2
// (verified absmax 0.0). Do not touch.
// ---------------------------------------------------------------------------
__global__ __launch_bounds__(256) void decode_kernel(
    const float* __restrict__ cls_feat, const float* __restrict__ reg_feat,
    const float* __restrict__ obj_w, const float* __restrict__ obj_b,
    const float* __restrict__ cls_w, const float* __restrict__ cls_b,
    const float* __restrict__ reg_w, const float* __restrict__ reg_b,
    float* __restrict__ out, unsigned* __restrict__ cnt,
    unsigned long long* __restrict__ keys)
{
    __shared__ float lds[512 * 28];   // weights [c][28]; reused for partials
    const int tid = threadIdx.x;

    for (int i = tid; i < 25 * 512; i += 256) {
        int o = i >> 9, c = i & 511;
        float v;
        if (o == 0)        v = obj_w[c];
        else if (o < 21)   v = cls_w[(o - 1) * 512 + c];
        else               v = reg_w[(o - 21) * 512 + c];
        lds[c * 28 + o] = v;
    }
    __syncthreads();

    const int posL  = tid & 31;
    const int chunk = tid >> 5;
    const int p     = blockIdx.x * 32 + posL;
    const int cb    = chunk * 64;

    float acc[NOUT];
#pragma unroll
    for (int o = 0; o < NOUT; ++o) acc[o] = 0.f;

    const float* cf = cls_feat + cb * HW + p;
    const float* rf = reg_feat + cb * HW + p;

#pragma unroll 4
    for (int k = 0; k < 64; ++k) {
        float f = cf[k * HW];
        float g = rf[k * HW];
        const float4* w = (const float4*)(lds + (cb + k) * 28);
        float4 w0 = w[0], w1 = w[1], w2 = w[2], w3 = w[3], w4v = w[4], w5 = w[5], w6 = w[6];
        acc[0]  += f * w0.x;  acc[1]  += f * w0.y;  acc[2]  += f * w0.z;  acc[3]  += f * w0.w;
        acc[4]  += f * w1.x;  acc[5]  += f * w1.y;  acc[6]  += f * w1.z;  acc[7]  += f * w1.w;
        acc[8]  += f * w2.x;  acc[9]  += f * w2.y;  acc[10] += f * w2.z;  acc[11] += f * w2.w;
        acc[12] += f * w3.x;  acc[13] += f * w3.y;  acc[14] += f * w3.z;  acc[15] += f * w3.w;
        acc[16] += f * w4v.x; acc[17] += f * w4v.y; acc[18] += f * w4v.z; acc[19] += f * w4v.w;
        acc[20] += f * w5.x;
        acc[21] += g * w5.y;  acc[22] += g * w5.z;  acc[23] += g * w5.w;  acc[24] += g * w6.x;
    }

    __syncthreads();
    float* part = lds;                  // [chunk][pos][25]
#pragma unroll
    for (int o = 0; o < NOUT; ++o) part[(chunk * 32 + posL) * NOUT + o] = acc[o];
    __syncthreads();

    float* dots = lds + 8 * 32 * NOUT;  // [pos][25]
    for (int t = tid; t < 32 * NOUT; t += 256) {
        int pos = t / NOUT, o = t - pos * NOUT;
        float s = 0.f;
#pragma unroll
        for (int c2 = 0; c2 < 8; ++c2) s += part[(c2 * 32 + pos) * NOUT + o];
        dots[t] = s;
    }
    __syncthreads();

    if (tid < 32) {
        const int pos = tid;
        const int pp  = blockIdx.x * 32 + pos;
        const float* d = dots + pos * NOUT;

        float obj  = d[0] + obj_b[0];
        float best = d[1] + cls_b[0];
        int   bk   = 0;
#pragma unroll
        for (int k = 1; k < NCLS; ++k) {
            float v = d[1 + k] + cls_b[k];
            if (v > best) { best = v; bk = k; }
        }
        float sobj  = 1.f / (1.f + expf(-obj));
        float scls  = 1.f / (1.f + expf(-best));
        float score = sobj * scls;

        float r0 = d[21] + reg_b[0], r1 = d[22] + reg_b[1];
        float r2 = d[23] + reg_b[2], r3 = d[24] + reg_b[3];
        float gx = (float)(pp % WIDTH), gy = (float)(pp / WIDTH);
        float cx = (1.f / (1.f + expf(-r0)) + gx) * 32.f;
        float cy = (1.f / (1.f + expf(-r1)) + gy) * 32.f;
        float bw = expf(r2) * 32.f;
        float bh = expf(r3) * 32.f;
        float hx = 0.5f * bw, hy = 0.5f * bh;

        ((float4*)out)[pp] = make_float4(cx - hx, cy - hy, cx + hx, cy + hy);
        out[HW * 4 + pp] = score;
        out[HW * 5 + pp] = (float)bk;
        out[HW * 6 + pp] = 0.f;

        if (score >= 0.01f) {
            unsigned slot = atomicAdd(&cnt[bk], 1u);
            if (slot < CAP) {
                unsigned sb = __float_as_uint(score) ^ 0xffffffffu;
                keys[bk * CAP + slot] = ((unsigned long long)sb << 32) | (unsigned)pp;
            }
        }
    }
}

// ---------------------------------------------------------------------------
// K2: per-class bitonic sort (unchanged from round 2).
// ---------------------------------------------------------------------------
__global__ __launch_bounds__(512) void sort_kernel(
    const unsigned* __restrict__ cnt, unsigned long long* __restrict__ keys)
{
    __shared__ unsigned long long a[CAP];
    const int c = blockIdx.x, t = threadIdx.x;
    unsigned m = cnt[c]; if (m > CAP) m = CAP;

    for (int i = t; i < CAP; i += 512)
        a[i] = (i < (int)m) ? keys[c * CAP + i] : 0xFFFFFFFFFFFFFFFFull;
    __syncthreads();

    for (int k = 2; k <= CAP; k <<= 1) {
        for (int j = k >> 1; j > 0; j >>= 1) {
            int i = ((t & ~(j - 1)) << 1) | (t & (j - 1));
            int p = i | j;
            unsigned long long x = a[i], y = a[p];
            bool up = ((i & k) == 0);
            if ((x > y) == up) { a[i] = y; a[p] = x; }
            __syncthreads();
        }
    }
    for (int i = t; i < (int)m; i += 512) keys[c * CAP + i] = a[i];
}

// ---------------------------------------------------------------------------
// K3a: parallel mask build. grid = NCLS*16 (class, 64-row tile), 1024 thr.
// Whole-chip parallel: each wave computes 64 ballot-words. Identical IoU
// expression to the verified round-2 kernel.
// ---------------------------------------------------------------------------
__global__ __launch_bounds__(1024) void build_kernel(
    const unsigned* __restrict__ cnt, const unsigned long long* __restrict__ keys,
    const float* __restrict__ bboxes, unsigned long long* __restrict__ mask)
{
    __shared__ float4 box[CAP];
    const int c = blockIdx.x >> 4, tile = blockIdx.x & 15;
    const int tid = threadIdx.x, wave = tid >> 6, lane = tid & 63;
    int m = (int)cnt[c]; if (m > CAP) m = CAP;
    const int rbase = tile << 6;
    if (rbase >= m) return;                      // uniform; before any barrier

    if (tid < m) {
        unsigned idx = (unsigned)(keys[c * CAP + tid] & 0xffffffffu);
        box[tid] = ((const float4*)bboxes)[idx];
    } else {
        box[tid] = make_float4(0.f, 0.f, 0.f, 0.f);
    }
    __syncthreads();

    unsigned long long* mrow = mask + (size_t)c * CAP * NW;
#pragma unroll 4
    for (int j = 0; j < 64; ++j) {
        const int row = rbase + (wave << 2) + (j >> 4);   // uniform per wave
        const int w   = j & 15;
        const float4 bi = box[row];
        const float4 bj = box[(w << 6) + lane];
        const float ai = (bi.z - bi.x) * (bi.w - bi.y);
        const float aj = (bj.z - bj.x) * (bj.w - bj.y);
        float iw = fminf(bi.z, bj.z) - fmaxf(bi.x, bj.x);
        float ih = fminf(bi.w, bj.w) - fmaxf(bi.y, bj.y);
        iw = fmaxf(iw, 1e-10f);
        ih = fmaxf(ih, 1e-10f);
        const float inter = iw * ih;
        const float iou = inter / (ai + aj - inter);
        unsigned long long word =
            __ballot((row < m) && (((w << 6) + lane) < m) && (iou > 0.5f));
        if (lane == 0) mrow[row * NW + w] = word;
    }
}

// ---------------------------------------------------------------------------
// K3b: greedy sweep, 1 wave per class. Scalar-register cascade via readlane;
// cross-word accumulation = one coalesced 128B row read per kept box.
// ---------------------------------------------------------------------------
__device__ __forceinline__ unsigned long long uread64(unsigned long long v, int srclane) {
    unsigned lo = __builtin_amdgcn_readlane((unsigned)v, srclane);
    unsigned hi = __builtin_amdgcn_readlane((unsigned)(v >> 32), srclane);
    return ((unsigned long long)hi << 32) | lo;
}

__global__ __launch_bounds__(64) void sweep_kernel(
    const unsigned* __restrict__ cnt, const unsigned long long* __restrict__ keys,
    const unsigned long long* __restrict__ mask, float* __restrict__ keep)
{
    __shared__ unsigned lidx[CAP];
    const int c = blockIdx.x, lane = threadIdx.x;
    int m = (int)cnt[c]; if (m > CAP) m = CAP;
    const int nw = (m + 63) >> 6;
    const unsigned long long* mrow = mask + (size_t)c * CAP * NW;

    for (int j = lane; j < m; j += 64)
        lidx[j] = (unsigned)(keys[c * CAP + j] & 0xffffffffu);
    __syncthreads();

    unsigned long long remw = 0;          // lane l holds rem word l (l < NW)
    for (int w = 0; w < nw; ++w) {
        const int i0 = w << 6;
        const int nb = min(64, m - i0);

        unsigned long long myrow = (lane < nb) ? mrow[(i0 + lane) * NW + w] : 0ull;
        unsigned long long cur  = uread64(remw, w);   // rem[w], uniform scalar
        unsigned long long kept = 0;
#pragma unroll
        for (int b = 0; b < 64; ++b) {
            unsigned long long v = uread64(myrow, b);          // row (i0+b) word w
            unsigned long long alive = ((cur >> b) & 1ull) ^ 1ull;
            kept |= alive << b;
            cur |= v & (0ull - alive);
        }
        if (nb < 64) kept &= (1ull << nb) - 1ull;

        if (lane < nb && ((kept >> lane) & 1ull))
            keep[lidx[i0 + lane]] = 1.0f;

        if (lane < nw) {                   // lane l accumulates word l
            unsigned long long k2 = kept, acc = remw;
            while (k2) {                   // uniform loop (kept is uniform)
                int b = __builtin_ctzll(k2);
                acc |= mrow[(i0 + b) * NW + lane];   // coalesced 128B row
                k2 &= k2 - 1;
            }
            remw = acc;
        }
    }
}

// ---------------------------------------------------------------------------
extern "C" void kernel_launch(void* const* d_in, const int* in_sizes, int n_in,
                              void* d_out, int out_size, void* d_ws, size_t ws_size,
                              hipStream_t stream)
{
    const float* cls_feat = (const float*)d_in[0];
    const float* reg_feat = (const float*)d_in[1];
    const float* obj_w    = (const float*)d_in[2];
    const float* obj_b    = (const float*)d_in[3];
    const float* cls_w    = (const float*)d_in[4];
    const float* cls_b    = (const float*)d_in[5];
    const float* reg_w    = (const float*)d_in[6];
    const float* reg_b    = (const float*)d_in[7];

    float* out = (float*)d_out;
    unsigned* cnt = (unsigned*)d_ws;
    unsigned long long* keys = (unsigned long long*)((char*)d_ws + 256);
    unsigned long long* mask = (unsigned long long*)((char*)d_ws + 256 + NCLS * CAP * 8);

    hipMemsetAsync(d_ws, 0, 256, stream);   // zero per-class counters

    decode_kernel<<<288, 256, 0, stream>>>(cls_feat, reg_feat, obj_w, obj_b,
                                           cls_w, cls_b, reg_w, reg_b,
                                           out, cnt, keys);
    sort_kernel<<<NCLS, 512, 0, stream>>>(cnt, keys);
    build_kernel<<<NCLS * 16, 1024, 0, stream>>>(cnt, keys, out, mask);
    sweep_kernel<<<NCLS, 64, 0, stream>>>(cnt, keys, mask, out + HW * 6);
}

// Round 4
// 187.474 us; speedup vs baseline: 3.5247x; 1.2178x over previous
//
#include <hip/hip_runtime.h>

#define HW 9216
#define WIDTH 96
#define NCLS 20
#define NOUT 25   // 1 obj + 20 cls + 4 reg
#define CAP 1024
#define NW 16     // CAP/64 mask words per row

// ---------------------------------------------------------------------------
// K1: fused GEMM (9216 x 512 x 25) + decode. BYTE-IDENTICAL to round-2/3
// (verified absmax 0.0). Do not touch.
// ---------------------------------------------------------------------------
__global__ __launch_bounds__(256) void decode_kernel(
    const float* __restrict__ cls_feat, const float* __restrict__ reg_feat,
    const float* __restrict__ obj_w, const float* __restrict__ obj_b,
    const float* __restrict__ cls_w, const float* __restrict__ cls_b,
    const float* __restrict__ reg_w, const float* __restrict__ reg_b,
    float* __restrict__ out, unsigned* __restrict__ cnt,
    unsigned long long* __restrict__ keys)
{
    __shared__ float lds[512 * 28];   // weights [c][28]; reused for partials
    const int tid = threadIdx.x;

    for (int i = tid; i < 25 * 512; i += 256) {
        int o = i >> 9, c = i & 511;
        float v;
        if (o == 0)        v = obj_w[c];
        else if (o < 21)   v = cls_w[(o - 1) * 512 + c];
        else               v = reg_w[(o - 21) * 512 + c];
        lds[c * 28 + o] = v;
    }
    __syncthreads();

    const int posL  = tid & 31;
    const int chunk = tid >> 5;
    const int p     = blockIdx.x * 32 + posL;
    const int cb    = chunk * 64;

    float acc[NOUT];
#pragma unroll
    for (int o = 0; o < NOUT; ++o) acc[o] = 0.f;

    const float* cf = cls_feat + cb * HW + p;
    const float* rf = reg_feat + cb * HW + p;

#pragma unroll 4
    for (int k = 0; k < 64; ++k) {
        float f = cf[k * HW];
        float g = rf[k * HW];
        const float4* w = (const float4*)(lds + (cb + k) * 28);
        float4 w0 = w[0], w1 = w[1], w2 = w[2], w3 = w[3], w4v = w[4], w5 = w[5], w6 = w[6];
        acc[0]  += f * w0.x;  acc[1]  += f * w0.y;  acc[2]  += f * w0.z;  acc[3]  += f * w0.w;
        acc[4]  += f * w1.x;  acc[5]  += f * w1.y;  acc[6]  += f * w1.z;  acc[7]  += f * w1.w;
        acc[8]  += f * w2.x;  acc[9]  += f * w2.y;  acc[10] += f * w2.z;  acc[11] += f * w2.w;
        acc[12] += f * w3.x;  acc[13] += f * w3.y;  acc[14] += f * w3.z;  acc[15] += f * w3.w;
        acc[16] += f * w4v.x; acc[17] += f * w4v.y; acc[18] += f * w4v.z; acc[19] += f * w4v.w;
        acc[20] += f * w5.x;
        acc[21] += g * w5.y;  acc[22] += g * w5.z;  acc[23] += g * w5.w;  acc[24] += g * w6.x;
    }

    __syncthreads();
    float* part = lds;                  // [chunk][pos][25]
#pragma unroll
    for (int o = 0; o < NOUT; ++o) part[(chunk * 32 + posL) * NOUT + o] = acc[o];
    __syncthreads();

    float* dots = lds + 8 * 32 * NOUT;  // [pos][25]
    for (int t = tid; t < 32 * NOUT; t += 256) {
        int pos = t / NOUT, o = t - pos * NOUT;
        float s = 0.f;
#pragma unroll
        for (int c2 = 0; c2 < 8; ++c2) s += part[(c2 * 32 + pos) * NOUT + o];
        dots[t] = s;
    }
    __syncthreads();

    if (tid < 32) {
        const int pos = tid;
        const int pp  = blockIdx.x * 32 + pos;
        const float* d = dots + pos * NOUT;

        float obj  = d[0] + obj_b[0];
        float best = d[1] + cls_b[0];
        int   bk   = 0;
#pragma unroll
        for (int k = 1; k < NCLS; ++k) {
            float v = d[1 + k] + cls_b[k];
            if (v > best) { best = v; bk = k; }
        }
        float sobj  = 1.f / (1.f + expf(-obj));
        float scls  = 1.f / (1.f + expf(-best));
        float score = sobj * scls;

        float r0 = d[21] + reg_b[0], r1 = d[22] + reg_b[1];
        float r2 = d[23] + reg_b[2], r3 = d[24] + reg_b[3];
        float gx = (float)(pp % WIDTH), gy = (float)(pp / WIDTH);
        float cx = (1.f / (1.f + expf(-r0)) + gx) * 32.f;
        float cy = (1.f / (1.f + expf(-r1)) + gy) * 32.f;
        float bw = expf(r2) * 32.f;
        float bh = expf(r3) * 32.f;
        float hx = 0.5f * bw, hy = 0.5f * bh;

        ((float4*)out)[pp] = make_float4(cx - hx, cy - hy, cx + hx, cy + hy);
        out[HW * 4 + pp] = score;
        out[HW * 5 + pp] = (float)bk;
        out[HW * 6 + pp] = 0.f;

        if (score >= 0.01f) {
            unsigned slot = atomicAdd(&cnt[bk], 1u);
            if (slot < CAP) {
                unsigned sb = __float_as_uint(score) ^ 0xffffffffu;
                keys[bk * CAP + slot] = ((unsigned long long)sb << 32) | (unsigned)pp;
            }
        }
    }
}

// ---------------------------------------------------------------------------
// K2: per-class bitonic sort (unchanged).
// ---------------------------------------------------------------------------
__global__ __launch_bounds__(512) void sort_kernel(
    const unsigned* __restrict__ cnt, unsigned long long* __restrict__ keys)
{
    __shared__ unsigned long long a[CAP];
    const int c = blockIdx.x, t = threadIdx.x;
    unsigned m = cnt[c]; if (m > CAP) m = CAP;

    for (int i = t; i < CAP; i += 512)
        a[i] = (i < (int)m) ? keys[c * CAP + i] : 0xFFFFFFFFFFFFFFFFull;
    __syncthreads();

    for (int k = 2; k <= CAP; k <<= 1) {
        for (int j = k >> 1; j > 0; j >>= 1) {
            int i = ((t & ~(j - 1)) << 1) | (t & (j - 1));
            int p = i | j;
            unsigned long long x = a[i], y = a[p];
            bool up = ((i & k) == 0);
            if ((x > y) == up) { a[i] = y; a[p] = x; }
            __syncthreads();
        }
    }
    for (int i = t; i < (int)m; i += 512) keys[c * CAP + i] = a[i];
}

// ---------------------------------------------------------------------------
// K3a: parallel mask build (unchanged from round 3).
// ---------------------------------------------------------------------------
__global__ __launch_bounds__(1024) void build_kernel(
    const unsigned* __restrict__ cnt, const unsigned long long* __restrict__ keys,
    const float* __restrict__ bboxes, unsigned long long* __restrict__ mask)
{
    __shared__ float4 box[CAP];
    const int c = blockIdx.x >> 4, tile = blockIdx.x & 15;
    const int tid = threadIdx.x, wave = tid >> 6, lane = tid & 63;
    int m = (int)cnt[c]; if (m > CAP) m = CAP;
    const int rbase = tile << 6;
    if (rbase >= m) return;                      // uniform; before any barrier

    if (tid < m) {
        unsigned idx = (unsigned)(keys[c * CAP + tid] & 0xffffffffu);
        box[tid] = ((const float4*)bboxes)[idx];
    } else {
        box[tid] = make_float4(0.f, 0.f, 0.f, 0.f);
    }
    __syncthreads();

    unsigned long long* mrow = mask + (size_t)c * CAP * NW;
#pragma unroll 4
    for (int j = 0; j < 64; ++j) {
        const int row = rbase + (wave << 2) + (j >> 4);   // uniform per wave
        const int w   = j & 15;
        const float4 bi = box[row];
        const float4 bj = box[(w << 6) + lane];
        const float ai = (bi.z - bi.x) * (bi.w - bi.y);
        const float aj = (bj.z - bj.x) * (bj.w - bj.y);
        float iw = fminf(bi.z, bj.z) - fmaxf(bi.x, bj.x);
        float ih = fminf(bi.w, bj.w) - fmaxf(bi.y, bj.y);
        iw = fmaxf(iw, 1e-10f);
        ih = fmaxf(ih, 1e-10f);
        const float inter = iw * ih;
        const float iou = inter / (ai + aj - inter);
        unsigned long long word =
            __ballot((row < m) && (((w << 6) + lane) < m) && (iou > 0.5f));
        if (lane == 0) mrow[row * NW + w] = word;
    }
}

// ---------------------------------------------------------------------------
// K3b: greedy sweep, 1 wave per class. All loads address-independent and
// fully unrolled (issued before the serial cascade -> latency hidden);
// accumulation is branch-free masked-OR + shfl_xor OR-reduce.
// ---------------------------------------------------------------------------
__device__ __forceinline__ unsigned long long uread64(unsigned long long v, int srclane) {
    unsigned lo = __builtin_amdgcn_readlane((unsigned)v, srclane);
    unsigned hi = __builtin_amdgcn_readlane((unsigned)(v >> 32), srclane);
    return ((unsigned long long)hi << 32) | lo;
}

__device__ __forceinline__ unsigned long long shflxor64(unsigned long long v, int m) {
    unsigned lo = __shfl_xor((unsigned)v, m, 64);
    unsigned hi = __shfl_xor((unsigned)(v >> 32), m, 64);
    return ((unsigned long long)hi << 32) | lo;
}

__global__ __launch_bounds__(64) void sweep_kernel(
    const unsigned* __restrict__ cnt, const unsigned long long* __restrict__ keys,
    const unsigned long long* __restrict__ mask, float* __restrict__ keep)
{
    const int c = blockIdx.x, lane = threadIdx.x;
    int m = (int)cnt[c]; if (m > CAP) m = CAP;
    const int nw = (m + 63) >> 6;
    const unsigned long long* mrow = mask + (size_t)c * CAP * NW;

    const int wsel = lane & 15;      // which mask word this lane gathers
    const int rof  = lane >> 4;      // row offset within groups of 4

    unsigned long long remw = 0;     // lane l holds rem word l (l < NW)
    for (int w = 0; w < nw; ++w) {
        const int i0 = w << 6;
        const int nb = min(64, m - i0);

        // my key (for keep-write), my diagonal word (for cascade)
        unsigned long long mykey =
            (lane < nb) ? keys[c * CAP + i0 + lane] : 0ull;
        unsigned long long myrow =
            (lane < nb) ? mrow[(size_t)(i0 + lane) * NW + w] : 0ull;

        // whole 64-row x 16-word mask block, 16 independent coalesced loads
        unsigned long long rw[16];
#pragma unroll
        for (int j = 0; j < 16; ++j) {
            const int r = i0 + rof + (j << 2);
            rw[j] = (r < m && wsel < nw)
                        ? mrow[(size_t)r * NW + wsel] : 0ull;
        }

        // serial cascade in uniform registers (identical recurrence)
        unsigned long long cur  = uread64(remw, w);
        unsigned long long kept = 0;
#pragma unroll
        for (int b = 0; b < 64; ++b) {
            unsigned long long v = uread64(myrow, b);
            unsigned long long alive = ((cur >> b) & 1ull) ^ 1ull;
            kept |= alive << b;
            cur |= v & (0ull - alive);
        }
        if (nb < 64) kept &= (1ull << nb) - 1ull;

        if (lane < nb && ((kept >> lane) & 1ull))
            keep[(unsigned)(mykey & 0xffffffffu)] = 1.0f;

        // branch-free OR of kept rows into rem, via register tile + reduce
        unsigned long long part = 0;
#pragma unroll
        for (int j = 0; j < 16; ++j) {
            const int b = rof + (j << 2);
            part |= rw[j] & (0ull - ((kept >> b) & 1ull));
        }
        part |= shflxor64(part, 16);
        part |= shflxor64(part, 32);
        if (lane < NW) remw |= part;   // lane l == word l (wsel==lane for l<16)
    }
}

// ---------------------------------------------------------------------------
extern "C" void kernel_launch(void* const* d_in, const int* in_sizes, int n_in,
                              void* d_out, int out_size, void* d_ws, size_t ws_size,
                              hipStream_t stream)
{
    const float* cls_feat = (const float*)d_in[0];
    const float* reg_feat = (const float*)d_in[1];
    const float* obj_w    = (const float*)d_in[2];
    const float* obj_b    = (const float*)d_in[3];
    const float* cls_w    = (const float*)d_in[4];
    const float* cls_b    = (const float*)d_in[5];
    const float* reg_w    = (const float*)d_in[6];
    const float* reg_b    = (const float*)d_in[7];

    float* out = (float*)d_out;
    unsigned* cnt = (unsigned*)d_ws;
    unsigned long long* keys = (unsigned long long*)((char*)d_ws + 256);
    unsigned long long* mask = (unsigned long long*)((char*)d_ws + 256 + NCLS * CAP * 8);

    hipMemsetAsync(d_ws, 0, 256, stream);   // zero per-class counters

    decode_kernel<<<288, 256, 0, stream>>>(cls_feat, reg_feat, obj_w, obj_b,
                                           cls_w, cls_b, reg_w, reg_b,
                                           out, cnt, keys);
    sort_kernel<<<NCLS, 512, 0, stream>>>(cnt, keys);
    build_kernel<<<NCLS * 16, 1024, 0, stream>>>(cnt, keys, out, mask);
    sweep_kernel<<<NCLS, 64, 0, stream>>>(cnt, keys, mask, out + HW * 6);
}